// Round 7
// baseline (360.795 us; speedup 1.0000x reference)
//
#include <hip/hip_runtime.h>
#include <hip/hip_bf16.h>

// SpatialRelation on MI355X — round 11.
// R10 (M=64 + barrier-diet + fin/eout rewrite) FAILED absmax (3.0e-2) and
// its traffic math was net-neutral anyway (A-dup 4x cancels weight savings).
// R11 = verified R9 base (350.5us, absmax 7.8e-3) + ONE math-identical
// change on the confirmed lever (request count): cache the step-invariant
// link + Wh weight B-fragments in registers across the 3 GRU steps
// (24 frags = 96 VGPRs; R9 ran 124/256 cap). Saves 48 of 168 per-wave
// step weight loads (block requests 1504 -> ~1312).

typedef unsigned short u16;
typedef __attribute__((ext_vector_type(4))) float f32x4;
typedef __attribute__((ext_vector_type(8))) short bf16x8;

#define DI static __device__ __forceinline__

DI u16 f2bf(float f) {
    unsigned u = __builtin_bit_cast(unsigned, f);
    return (u16)((u + 0x7fffu + ((u >> 16) & 1u)) >> 16);  // RNE
}

DI bf16x8 cvt8(float4 a, float4 b) {
    u16 tmp[8] = {f2bf(a.x), f2bf(a.y), f2bf(a.z), f2bf(a.w),
                  f2bf(b.x), f2bf(b.y), f2bf(b.z), f2bf(b.w)};
    return *(const bf16x8*)tmp;
}

// B-operand image: element (k,n) at (((k>>5)*128+n)*4 + (((k>>3)&3)^((n>>1)&3)))*8 + (k&7)
DI int imgIdx(int k, int n) {
    return (((k >> 5) * 128 + n) * 4 + (((k >> 3) & 3) ^ ((n >> 1) & 3))) * 8 + (k & 7);
}
// B fragment (16B) direct from a weight/edge image in global memory.
DI bf16x8 wfragG(const u16* __restrict__ img, int kc, int tt, int l15, int quad) {
    return *(const bf16x8*)&img[(((kc * 128 + tt * 16 + l15) * 4) + (quad ^ ((l15 >> 1) & 3))) * 8];
}

#define MFMA16(a, b, c) __builtin_amdgcn_mfma_f32_16x16x32_bf16(a, b, c, 0, 0, 0)

// ---------------------------------------------------------------- prep 1
__global__ __launch_bounds__(256) void k_prep1(
    const float* __restrict__ linkW, const float* __restrict__ resetW,
    const float* __restrict__ updateW, const float* __restrict__ transW,
    const float* __restrict__ attW1, const float* __restrict__ outW,
    float* __restrict__ W2, u16* __restrict__ linkImg, u16* __restrict__ WrImg,
    u16* __restrict__ WzImg, u16* __restrict__ WhImg, u16* __restrict__ attW1Img,
    u16* __restrict__ outWImg)
{
    int blk = blockIdx.x, t = threadIdx.x;
    if (blk < 256) {
        int idx = blk * 256 + t;
        int out = idx >> 2, q = idx & 3;
        int r = out >> 7, c = out & 127;
        const float* ar = linkW + r * 128 + q * 32;
        float acc = 0.f;
#pragma unroll
        for (int k = 0; k < 32; k++) acc += ar[k] * linkW[(q * 32 + k) * 128 + c];
        acc += __shfl_xor(acc, 1);
        acc += __shfl_xor(acc, 2);
        if (q == 0) W2[out] = acc;
    } else {
        const float* src; u16* dst; int base;
        if (blk < 260)      { src = resetW;  dst = WrImg;    base = 256; }
        else if (blk < 264) { src = updateW; dst = WzImg;    base = 260; }
        else if (blk < 268) { src = transW;  dst = WhImg;    base = 264; }
        else if (blk < 270) { src = linkW;   dst = linkImg;  base = 268; }
        else if (blk < 272) { src = attW1;   dst = attW1Img; base = 270; }
        else                { src = outW;    dst = outWImg;  base = 272; }
        int off = (blk - base) * 8192;
        for (int i = 0; i < 32; i++) {
            int e = off + t + i * 256;
            int k = e >> 7, n = e & 127;
            dst[imgIdx(k, n)] = f2bf(src[e]);
        }
    }
}

// ---------------------------------------------------------------- prep 2
__global__ __launch_bounds__(256) void k_prep2(
    const float* __restrict__ linkW, const float* __restrict__ linkb,
    const float* __restrict__ W2, u16* __restrict__ W3Img, float* __restrict__ ebias)
{
    int blk = blockIdx.x, t = threadIdx.x;
    if (blk < 256) {
        int idx = blk * 256 + t;
        int out = idx >> 2, q = idx & 3;
        int r = out >> 7, c = out & 127;
        const float* ar = W2 + r * 128 + q * 32;
        float acc = 0.f;
#pragma unroll
        for (int k = 0; k < 32; k++) acc += ar[k] * linkW[(q * 32 + k) * 128 + c];
        acc += __shfl_xor(acc, 1);
        acc += __shfl_xor(acc, 2);
        if (q == 0) W3Img[imgIdx(r, c)] = f2bf(acc);
    } else if (t < 128) {
        float acc = linkb[t];
#pragma unroll 8
        for (int k = 0; k < 128; k++) acc += linkb[k] * (W2[k * 128 + t] + linkW[k * 128 + t]);
        ebias[t] = acc;
    }
}

// ---------------------------------------------------------------- E transpose (+edge resid)
__global__ __launch_bounds__(256) void k_te(
    const float* __restrict__ E0, u16* __restrict__ Eswz, float* __restrict__ resid)
{
    __shared__ alignas(16) u16 sT[4096];
    __shared__ float sCol[128];
    int t = threadIdx.x, kc = blockIdx.x, b = blockIdx.y;
    const float* Eb = E0 + (size_t)b * 262144 + (size_t)kc * 32 * 128;
    if (t < 128) sCol[t] = 0.f;
    float part[4] = {0.f, 0.f, 0.f, 0.f};
    int ncol = (t & 31) * 4;
    for (int i = 0; i < 4; i++) {
        int f4i = t + i * 256;
        int k5 = f4i >> 5;
        float4 v = *(const float4*)&Eb[k5 * 128 + ncol];
        int g = k5 >> 3, o = k5 & 7;
        float vv[4] = {v.x, v.y, v.z, v.w};
#pragma unroll
        for (int j = 0; j < 4; j++) {
            int n = ncol + j;
            sT[(n * 4 + (g ^ ((n >> 1) & 3))) * 8 + o] = f2bf(vv[j]);
            part[j] += vv[j];
        }
    }
    __syncthreads();
#pragma unroll
    for (int j = 0; j < 4; j++) atomicAdd(&sCol[ncol + j], part[j]);
    u16* dst = Eswz + (size_t)b * 262144 + (size_t)kc * 4096;
    ((uint4*)dst)[t] = ((const uint4*)sT)[t];
    ((uint4*)dst)[t + 256] = ((const uint4*)sT)[t + 256];
    __syncthreads();
    if (t < 128) atomicAdd(&resid[b * 128 + t], sCol[t]);
}

// ---------------------------------------------------------------- FUSED: G0 = A@E0 (32 rows),
// then 3 GRU steps + attention for both 16-row groups. Wave (tg,kh) in G0;
// wave = tt-pair in steps, iterating rg 0/1 so each weight fragment feeds
// 2x MFMAs. sBuf rows: 0-31 a | 32-63 p | 64-95 r*p.
// R11: link+Wh fragments register-cached across the 3 steps (bit-identical).
__global__ __launch_bounds__(256, 2) void k_main(
    const float* __restrict__ A, const u16* __restrict__ Eswz,
    const float* __restrict__ p0,
    const u16* __restrict__ linkImg, const u16* __restrict__ WrImg,
    const u16* __restrict__ WzImg, const u16* __restrict__ WhImg,
    const u16* __restrict__ attW1Img, const u16* __restrict__ outWImg,
    const float* __restrict__ link_b, const float* __restrict__ reset_b,
    const float* __restrict__ update_b, const float* __restrict__ trans_b,
    const float* __restrict__ att_b1, const float* __restrict__ att_W2,
    const float* __restrict__ att_b2, const float* __restrict__ out_b,
    float* __restrict__ atten, float* __restrict__ outPool,
    float* __restrict__ resid)
{
    __shared__ float sAcc2[2][2][16 * 65];             // 16.6 KB: [tg][rg] K-half-1 partials
    __shared__ float sRs[2][32];                       // [kh][row] rowsum partials
    __shared__ alignas(16) u16 sBuf[96 * 136];         // 26.1 KB operand buffer
    __shared__ float sRed[32];

    int t = threadIdx.x, wid = t >> 6, lane = t & 63, l15 = lane & 15, quad = lane >> 4;
    int tg = wid >> 1, kh = wid & 1;                   // G0: tt-group / K-half
    int bx = blockIdx.x;
    int g = bx >> 7, rmod = bx & 127;
    int b = (rmod & 7) + 8 * g;                        // XCD-affine batch mapping
    int s = (rmod >> 3) & 15;
    size_t r0 = (size_t)b * 512 + (size_t)s * 32;

    // ================= phase G0: acc = A[32 rows] @ E0; B frags reused for both row-groups
    {
        const u16* Eb = Eswz + (size_t)b * 262144;
        const float* Ar0 = A + (r0 + l15) * 2048 + kh * 1024;
        const float* Ar1 = A + (r0 + 16 + l15) * 2048 + kh * 1024;

        f32x4 acc[2][4];
#pragma unroll
        for (int rg = 0; rg < 2; rg++)
#pragma unroll
            for (int i = 0; i < 4; i++) acc[rg][i] = (f32x4){0.f, 0.f, 0.f, 0.f};
        float rs0 = 0.f, rs1 = 0.f;

        float4 x0 = *(const float4*)&Ar0[quad * 8];
        float4 y0 = *(const float4*)&Ar0[quad * 8 + 4];
        float4 x1 = *(const float4*)&Ar1[quad * 8];
        float4 y1 = *(const float4*)&Ar1[quad * 8 + 4];
        rs0 += x0.x + x0.y + x0.z + x0.w + y0.x + y0.y + y0.z + y0.w;
        rs1 += x1.x + x1.y + x1.z + x1.w + y1.x + y1.y + y1.z + y1.w;
        bf16x8 aF0 = cvt8(x0, y0), aF1 = cvt8(x1, y1);
        bf16x8 bc[4];
#pragma unroll
        for (int tt = 0; tt < 4; tt++) bc[tt] = wfragG(Eb, kh * 32, tg * 4 + tt, l15, quad);

        for (int kc = 0; kc < 32; kc++) {
            float4 xn0, yn0, xn1, yn1; bf16x8 bn[4];
            if (kc < 31) {
                xn0 = *(const float4*)&Ar0[(kc + 1) * 32 + quad * 8];
                yn0 = *(const float4*)&Ar0[(kc + 1) * 32 + quad * 8 + 4];
                xn1 = *(const float4*)&Ar1[(kc + 1) * 32 + quad * 8];
                yn1 = *(const float4*)&Ar1[(kc + 1) * 32 + quad * 8 + 4];
#pragma unroll
                for (int tt = 0; tt < 4; tt++)
                    bn[tt] = wfragG(Eb, kh * 32 + kc + 1, tg * 4 + tt, l15, quad);
            }
#pragma unroll
            for (int tt = 0; tt < 4; tt++) {
                acc[0][tt] = MFMA16(aF0, bc[tt], acc[0][tt]);
                acc[1][tt] = MFMA16(aF1, bc[tt], acc[1][tt]);
            }
            if (kc < 31) {
                rs0 += xn0.x + xn0.y + xn0.z + xn0.w + yn0.x + yn0.y + yn0.z + yn0.w;
                rs1 += xn1.x + xn1.y + xn1.z + xn1.w + yn1.x + yn1.y + yn1.z + yn1.w;
                aF0 = cvt8(xn0, yn0); aF1 = cvt8(xn1, yn1);
#pragma unroll
                for (int tt = 0; tt < 4; tt++) bc[tt] = bn[tt];
            }
        }
        rs0 += __shfl_xor(rs0, 16); rs0 += __shfl_xor(rs0, 32);
        rs1 += __shfl_xor(rs1, 16); rs1 += __shfl_xor(rs1, 32);
        if (quad == 0 && tg == 0) { sRs[kh][l15] = rs0; sRs[kh][16 + l15] = rs1; }
        if (kh == 1) {
#pragma unroll
            for (int rg = 0; rg < 2; rg++)
#pragma unroll
                for (int tt = 0; tt < 4; tt++)
#pragma unroll
                    for (int r = 0; r < 4; r++)
                        sAcc2[tg][rg][(quad * 4 + r) * 65 + tt * 16 + l15] = acc[rg][tt][r];
        }
        if (t < 32) sRed[t] = 0.f;                     // attention accumulator
        __syncthreads();
        if (kh == 0) {
            // combine K-halves, emit bf16 G0 into sBuf rows 0-31
#pragma unroll
            for (int rg = 0; rg < 2; rg++)
#pragma unroll
                for (int tt = 0; tt < 4; tt++)
#pragma unroll
                    for (int r = 0; r < 4; r++) {
                        float v = acc[rg][tt][r] + sAcc2[tg][rg][(quad * 4 + r) * 65 + tt * 16 + l15];
                        sBuf[(rg * 16 + quad * 4 + r) * 136 + tg * 64 + tt * 16 + l15] = f2bf(v);
                    }
        } else {
            // K-half-1 waves (128 threads) stage p0 -> sBuf rows 32-63
            int idx = tg * 64 + lane;                  // 0..127
            int row = idx >> 2, cq = (idx & 3) * 32;
            const float* pr = &p0[(r0 + row) * 128 + cq];
#pragma unroll
            for (int j = 0; j < 4; j++) {
                float4 x = *(const float4*)&pr[j * 8];
                float4 y = *(const float4*)&pr[j * 8 + 4];
                *(bf16x8*)&sBuf[(32 + row) * 136 + cq + j * 8] = cvt8(x, y);
            }
        }
    }
    __syncthreads();

    // ================= steps: 3 GRU steps + attention; wave owns tt-pair, loops rg 0/1
    int ttA = wid * 2, ttB = wid * 2 + 1;
    int colA = ttA * 16 + l15, colB = ttB * 16 + l15;

    // R11: register-cache step-invariant link + Wh fragments (bit-identical reuse)
    bf16x8 wlC[4][2], whC[8][2];
#pragma unroll
    for (int kc = 0; kc < 4; kc++) {
        wlC[kc][0] = wfragG(linkImg, kc, ttA, l15, quad);
        wlC[kc][1] = wfragG(linkImg, kc, ttB, l15, quad);
    }
#pragma unroll
    for (int kc = 0; kc < 8; kc++) {
        whC[kc][0] = wfragG(WhImg, kc, ttA, l15, quad);
        whC[kc][1] = wfragG(WhImg, kc, ttB, l15, quad);
    }

    // own-col fp32 p state for both row-groups
    f32x4 pS[2][2];
#pragma unroll
    for (int rg = 0; rg < 2; rg++)
#pragma unroll
        for (int j = 0; j < 2; j++)
#pragma unroll
            for (int r = 0; r < 4; r++)
                pS[rg][j][r] = p0[(r0 + rg * 16 + quad * 4 + r) * 128 + (wid * 2 + j) * 16 + l15];
    // node residual: sum over this block's 32 rows, own cols
    {
        float s0 = pS[0][0][0] + pS[0][0][1] + pS[0][0][2] + pS[0][0][3]
                 + pS[1][0][0] + pS[1][0][1] + pS[1][0][2] + pS[1][0][3];
        float s1 = pS[0][1][0] + pS[0][1][1] + pS[0][1][2] + pS[0][1][3]
                 + pS[1][1][0] + pS[1][1][1] + pS[1][1][2] + pS[1][1][3];
        s0 += __shfl_xor(s0, 16); s0 += __shfl_xor(s0, 32);
        s1 += __shfl_xor(s1, 16); s1 += __shfl_xor(s1, 32);
        if (quad == 0) {
            atomicAdd(&resid[b * 128 + colA], s0);
            atomicAdd(&resid[b * 128 + colB], s1);
        }
    }
    float sv[2][4];
#pragma unroll
    for (int rg = 0; rg < 2; rg++)
#pragma unroll
        for (int r = 0; r < 4; r++)
            sv[rg][r] = sRs[0][rg * 16 + quad * 4 + r] + sRs[1][rg * 16 + quad * 4 + r];
    float lbA = link_b[colA], lbB = link_b[colB];
    float rbA = reset_b[colA], rbB = reset_b[colB];
    float ubA = update_b[colA], ubB = update_b[colB];
    float tbA = trans_b[colA], tbB = trans_b[colB];

    f32x4 zero4 = {0.f, 0.f, 0.f, 0.f};
    int fcol = quad * 8;
    for (int step = 0; step < 3; step++) {
        // ---- phase 1: a_new = a @ linkW + rowsum*link_b (cached link frags)
        f32x4 cc[2][2];
#pragma unroll
        for (int rg = 0; rg < 2; rg++) { cc[rg][0] = zero4; cc[rg][1] = zero4; }
#pragma unroll
        for (int kc = 0; kc < 4; kc++) {
            bf16x8 af0 = *(const bf16x8*)&sBuf[l15 * 136 + kc * 32 + fcol];
            bf16x8 af1 = *(const bf16x8*)&sBuf[(16 + l15) * 136 + kc * 32 + fcol];
            cc[0][0] = MFMA16(af0, wlC[kc][0], cc[0][0]); cc[0][1] = MFMA16(af0, wlC[kc][1], cc[0][1]);
            cc[1][0] = MFMA16(af1, wlC[kc][0], cc[1][0]); cc[1][1] = MFMA16(af1, wlC[kc][1], cc[1][1]);
        }
        __syncthreads();             // reads of rows 0-31 done before rewrite
#pragma unroll
        for (int rg = 0; rg < 2; rg++)
#pragma unroll
            for (int r = 0; r < 4; r++) {
                sBuf[(rg * 16 + quad * 4 + r) * 136 + colA] = f2bf(cc[rg][0][r] + sv[rg][r] * lbA);
                sBuf[(rg * 16 + quad * 4 + r) * 136 + colB] = f2bf(cc[rg][1][r] + sv[rg][r] * lbB);
            }
        __syncthreads();             // a_new visible
        // ---- phase 2: r, z; K=256 over [a_new(0-31), p(32-63)] (global Wr/Wz)
        f32x4 rr[2][2], zz[2][2];
#pragma unroll
        for (int rg = 0; rg < 2; rg++) { rr[rg][0] = zero4; rr[rg][1] = zero4; zz[rg][0] = zero4; zz[rg][1] = zero4; }
#pragma unroll 4
        for (int kc = 0; kc < 8; kc++) {
            int base = (kc >> 2) * 32;
            bf16x8 wra = wfragG(WrImg, kc, ttA, l15, quad);
            bf16x8 wrb = wfragG(WrImg, kc, ttB, l15, quad);
            bf16x8 wza = wfragG(WzImg, kc, ttA, l15, quad);
            bf16x8 wzb = wfragG(WzImg, kc, ttB, l15, quad);
            bf16x8 af0 = *(const bf16x8*)&sBuf[(base + l15) * 136 + (kc & 3) * 32 + fcol];
            bf16x8 af1 = *(const bf16x8*)&sBuf[(base + 16 + l15) * 136 + (kc & 3) * 32 + fcol];
            rr[0][0] = MFMA16(af0, wra, rr[0][0]); rr[0][1] = MFMA16(af0, wrb, rr[0][1]);
            zz[0][0] = MFMA16(af0, wza, zz[0][0]); zz[0][1] = MFMA16(af0, wzb, zz[0][1]);
            rr[1][0] = MFMA16(af1, wra, rr[1][0]); rr[1][1] = MFMA16(af1, wrb, rr[1][1]);
            zz[1][0] = MFMA16(af1, wza, zz[1][0]); zz[1][1] = MFMA16(af1, wzb, zz[1][1]);
        }
#pragma unroll
        for (int rg = 0; rg < 2; rg++)
#pragma unroll
            for (int r = 0; r < 4; r++) {
                float rvA = 1.f / (1.f + __expf(-(rr[rg][0][r] + rbA)));
                float rvB = 1.f / (1.f + __expf(-(rr[rg][1][r] + rbB)));
                zz[rg][0][r] = 1.f / (1.f + __expf(-(zz[rg][0][r] + ubA)));
                zz[rg][1][r] = 1.f / (1.f + __expf(-(zz[rg][1][r] + ubB)));
                sBuf[(64 + rg * 16 + quad * 4 + r) * 136 + colA] = f2bf(rvA * pS[rg][0][r]);
                sBuf[(64 + rg * 16 + quad * 4 + r) * 136 + colB] = f2bf(rvB * pS[rg][1][r]);
            }
        __syncthreads();             // r*p (rows 64-95) visible
        // ---- phase 3: h; K=256 over [a_new(0-31), r*p(64-95)] (cached Wh frags)
        f32x4 hh[2][2];
#pragma unroll
        for (int rg = 0; rg < 2; rg++) { hh[rg][0] = zero4; hh[rg][1] = zero4; }
#pragma unroll
        for (int kc = 0; kc < 8; kc++) {
            int base = (kc >> 2) * 64;
            bf16x8 af0 = *(const bf16x8*)&sBuf[(base + l15) * 136 + (kc & 3) * 32 + fcol];
            bf16x8 af1 = *(const bf16x8*)&sBuf[(base + 16 + l15) * 136 + (kc & 3) * 32 + fcol];
            hh[0][0] = MFMA16(af0, whC[kc][0], hh[0][0]); hh[0][1] = MFMA16(af0, whC[kc][1], hh[0][1]);
            hh[1][0] = MFMA16(af1, whC[kc][0], hh[1][0]); hh[1][1] = MFMA16(af1, whC[kc][1], hh[1][1]);
        }
#pragma unroll
        for (int rg = 0; rg < 2; rg++)
#pragma unroll
            for (int r = 0; r < 4; r++) {
                float h1 = tanhf(hh[rg][0][r] + tbA), h2 = tanhf(hh[rg][1][r] + tbB);
                pS[rg][0][r] = (1.f - zz[rg][0][r]) * pS[rg][0][r] + zz[rg][0][r] * h1;
                pS[rg][1][r] = (1.f - zz[rg][1][r]) * pS[rg][1][r] + zz[rg][1][r] * h2;
                sBuf[(32 + rg * 16 + quad * 4 + r) * 136 + colA] = f2bf(pS[rg][0][r]);
                sBuf[(32 + rg * 16 + quad * 4 + r) * 136 + colB] = f2bf(pS[rg][1][r]);
            }
        __syncthreads();             // p (rows 32-63) visible
    }
    // ---- attention + out; A-operand = p3 (rows 32-63), weights shared across rgs
    f32x4 at[2][2], oo[2][2];
#pragma unroll
    for (int rg = 0; rg < 2; rg++) { at[rg][0] = zero4; at[rg][1] = zero4; oo[rg][0] = zero4; oo[rg][1] = zero4; }
#pragma unroll
    for (int kc = 0; kc < 4; kc++) {
        bf16x8 wa  = wfragG(attW1Img, kc, ttA, l15, quad);
        bf16x8 wb  = wfragG(attW1Img, kc, ttB, l15, quad);
        bf16x8 woa = wfragG(outWImg,  kc, ttA, l15, quad);
        bf16x8 wob = wfragG(outWImg,  kc, ttB, l15, quad);
        bf16x8 pf0 = *(const bf16x8*)&sBuf[(32 + l15) * 136 + kc * 32 + fcol];
        bf16x8 pf1 = *(const bf16x8*)&sBuf[(48 + l15) * 136 + kc * 32 + fcol];
        at[0][0] = MFMA16(pf0, wa, at[0][0]);  at[0][1] = MFMA16(pf0, wb, at[0][1]);
        oo[0][0] = MFMA16(pf0, woa, oo[0][0]); oo[0][1] = MFMA16(pf0, wob, oo[0][1]);
        at[1][0] = MFMA16(pf1, wa, at[1][0]);  at[1][1] = MFMA16(pf1, wb, at[1][1]);
        oo[1][0] = MFMA16(pf1, woa, oo[1][0]); oo[1][1] = MFMA16(pf1, wob, oo[1][1]);
    }
    float b1A = att_b1[colA], b1B = att_b1[colB];
    float w2A = att_W2[colA], w2B = att_W2[colB];
    float obA = out_b[colA],  obB = out_b[colB];
#pragma unroll
    for (int rg = 0; rg < 2; rg++)
#pragma unroll
        for (int r = 0; r < 4; r++) {
            float pr = tanhf(at[rg][0][r] + b1A) * w2A + tanhf(at[rg][1][r] + b1B) * w2B;
            outPool[(r0 + rg * 16 + quad * 4 + r) * 128 + colA] = tanhf(oo[rg][0][r] + obA);
            outPool[(r0 + rg * 16 + quad * 4 + r) * 128 + colB] = tanhf(oo[rg][1][r] + obB);
            float v = pr;
            v += __shfl_xor(v, 1); v += __shfl_xor(v, 2);
            v += __shfl_xor(v, 4); v += __shfl_xor(v, 8);
            if (l15 == 0) atomicAdd(&sRed[rg * 16 + quad * 4 + r], v);
        }
    __syncthreads();
    if (t < 32) atten[r0 + t] = sRed[t] + att_b2[0];
}

// ---------------------------------------------------------------- edges out: E0@W3 + ebias
// M=32: each W3 fragment feeds both row-groups (halves weight traffic).
__global__ __launch_bounds__(64) void k_eout(
    const float* __restrict__ E0, const u16* __restrict__ W3Img,
    const float* __restrict__ ebias, float* __restrict__ Eout)
{
    int t = threadIdx.x, l15 = t & 15, quad = t >> 4;
    size_t r0 = (size_t)blockIdx.x * 32;
    bf16x8 eF[2][4];
#pragma unroll
    for (int rg = 0; rg < 2; rg++)
#pragma unroll
        for (int kc = 0; kc < 4; kc++) {
            const float* er = &E0[(r0 + rg * 16 + l15) * 128 + kc * 32 + quad * 8];
            eF[rg][kc] = cvt8(*(const float4*)er, *(const float4*)(er + 4));
        }
    f32x4 acc[2][8];
#pragma unroll
    for (int rg = 0; rg < 2; rg++)
#pragma unroll
        for (int i = 0; i < 8; i++) acc[rg][i] = (f32x4){0.f, 0.f, 0.f, 0.f};
    {
        bf16x8 wc[8], wn[8];
#pragma unroll
        for (int tt = 0; tt < 8; tt++) wc[tt] = wfragG(W3Img, 0, tt, l15, quad);
#pragma unroll
        for (int kc = 0; kc < 4; kc++) {
            if (kc < 3)
#pragma unroll
                for (int tt = 0; tt < 8; tt++) wn[tt] = wfragG(W3Img, kc + 1, tt, l15, quad);
#pragma unroll
            for (int tt = 0; tt < 8; tt++) {
                acc[0][tt] = MFMA16(eF[0][kc], wc[tt], acc[0][tt]);
                acc[1][tt] = MFMA16(eF[1][kc], wc[tt], acc[1][tt]);
            }
            if (kc < 3)
#pragma unroll
                for (int tt = 0; tt < 8; tt++) wc[tt] = wn[tt];
        }
    }
#pragma unroll
    for (int tt = 0; tt < 8; tt++) {
        int col = tt * 16 + l15; float eb = ebias[col];
#pragma unroll
        for (int rg = 0; rg < 2; rg++)
#pragma unroll
            for (int r = 0; r < 4; r++)
                Eout[(r0 + rg * 16 + quad * 4 + r) * 128 + col] = acc[rg][tt][r] + eb;
    }
}

// ---------------------------------------------------------------- softmax-pool + residual
__global__ __launch_bounds__(1024) void k_fin(
    const float* __restrict__ atten, const float* __restrict__ outPool,
    const float* __restrict__ resid,
    float* __restrict__ outRes, float* __restrict__ outMul)
{
    __shared__ float swv[512];
    __shared__ float sred[512];
    __shared__ float sacc[8][128];
    int t = threadIdx.x, b = blockIdx.x;
    float a = 0.f;
    if (t < 512) { a = atten[b * 512 + t]; sred[t] = a; }
    __syncthreads();
    for (int s = 256; s > 0; s >>= 1) { if (t < s) sred[t] = fmaxf(sred[t], sred[t + s]); __syncthreads(); }
    float mx = sred[0]; __syncthreads();
    if (t < 512) { float e = __expf(a - mx); swv[t] = e; sred[t] = e; }
    __syncthreads();
    for (int s = 256; s > 0; s >>= 1) { if (t < s) sred[t] += sred[t + s]; __syncthreads(); }
    float Z = sred[0]; __syncthreads();
    int col = t & 127, q = t >> 7;                     // 8 row-groups of 64
    const float* op = outPool + ((size_t)b * 512 + q * 64) * 128 + col;
    float accM = 0.f;
#pragma unroll 8
    for (int n = 0; n < 64; n++) accM += swv[q * 64 + n] * op[(size_t)n * 128];
    sacc[q][col] = accM;
    __syncthreads();
    if (t < 128) {
        float mulv = (sacc[0][t] + sacc[1][t] + sacc[2][t] + sacc[3][t] +
                      sacc[4][t] + sacc[5][t] + sacc[6][t] + sacc[7][t]) / Z;
        float rv = resid[b * 128 + t] * (1.f / 2560.f);
        outMul[b * 128 + t] = mulv;
        outRes[b * 128 + t] = fmaxf(0.f, tanhf(mulv) + rv);
    }
}

// ================================================================ launch
extern "C" void kernel_launch(void* const* d_in, const int* in_sizes, int n_in,
                              void* d_out, int out_size, void* d_ws, size_t ws_size,
                              hipStream_t stream)
{
    const float* prop0  = (const float*)d_in[0];
    const float* edge0  = (const float*)d_in[1];
    const float* Amat   = (const float*)d_in[2];
    const float* linkW  = (const float*)d_in[4];
    const float* linkb  = (const float*)d_in[5];
    const float* resetW = (const float*)d_in[6];
    const float* resetb = (const float*)d_in[7];
    const float* updateW= (const float*)d_in[8];
    const float* updateb= (const float*)d_in[9];
    const float* transW = (const float*)d_in[10];
    const float* transb = (const float*)d_in[11];
    const float* attW1  = (const float*)d_in[12];
    const float* attb1  = (const float*)d_in[13];
    const float* attW2  = (const float*)d_in[14];
    const float* attb2  = (const float*)d_in[15];
    const float* outW   = (const float*)d_in[16];
    const float* outb   = (const float*)d_in[17];

    char* w = (char*)d_ws;
    float* ws_atten   = (float*)(w + 4259840);        //    65,536 B
    float* ws_resid   = (float*)(w + 4325376);        //    16,384 B
    float* ws_W2      = (float*)(w + 4341760);        //    65,536 B
    float* ws_ebias   = (float*)(w + 4407296);        //       512 B
    u16*   ws_linkImg = (u16*)(w + 4407808);          //    32,768 B
    u16*   ws_W3Img   = (u16*)(w + 4440576);          //    32,768 B
    u16*   ws_WrImg   = (u16*)(w + 4473344);          //    65,536 B
    u16*   ws_WzImg   = (u16*)(w + 4538880);          //    65,536 B
    u16*   ws_WhImg   = (u16*)(w + 4604416);          //    65,536 B
    u16*   ws_attW1Img= (u16*)(w + 4669952);          //    32,768 B
    u16*   ws_outWImg = (u16*)(w + 4702720);          //    32,768 B (~4.7 MB)

    float* out_res  = (float*)d_out;
    float* out_mul  = out_res + 4096;
    float* out_edge = out_res + 8192;
    // Scratch inside d_out edge region (dead until k_eout, which runs last):
    u16*   Eswz     = (u16*)out_edge;                 // 16.78 MB
    float* outPool  = out_edge + 4194304;             // next 8.39 MB

    hipMemsetAsync(ws_resid, 0, 32 * 128 * sizeof(float), stream);
    k_prep1<<<274, 256, 0, stream>>>(linkW, resetW, updateW, transW, attW1, outW,
                                     ws_W2, ws_linkImg, ws_WrImg, ws_WzImg, ws_WhImg,
                                     ws_attW1Img, ws_outWImg);
    k_prep2<<<257, 256, 0, stream>>>(linkW, linkb, ws_W2, ws_W3Img, ws_ebias);
    k_te<<<dim3(64, 32), 256, 0, stream>>>(edge0, Eswz, ws_resid);
    k_main<<<512, 256, 0, stream>>>(Amat, Eswz, prop0,
                                    ws_linkImg, ws_WrImg, ws_WzImg, ws_WhImg,
                                    ws_attW1Img, ws_outWImg,
                                    linkb, resetb, updateb, transb,
                                    attb1, attW2, attb2, outb,
                                    ws_atten, outPool, ws_resid);
    k_fin<<<32, 1024, 0, stream>>>(ws_atten, outPool, ws_resid, out_res, out_mul);
    k_eout<<<2048, 64, 0, stream>>>(edge0, ws_W3Img, ws_ebias, out_edge);
}

// Round 8
// 350.632 us; speedup vs baseline: 1.0290x; 1.0290x over previous
//
#include <hip/hip_runtime.h>
#include <hip/hip_bf16.h>

// SpatialRelation on MI355X — round 12.
// R11 (reg-cache weights) REGRESSED: spills (WRITE 8.5->27.5MB), k_main
// 102->143us. Reverted. R12 = verified R9 base (350.5us) + ONE change:
// cvt8 uses hw v_cvt_pk_bf16_f32 (4 instrs) instead of 8 manual integer-RNE
// f2bf (~36 VALU ops). G0 runs 128 cvt8/wave on the load->MFMA dependency
// path; VALUBusy 22% (3x MfmaUtil) says conversion is a top VALU block.
// RNE==RNE => bit-identical output layout (lo half = first elem).

typedef unsigned short u16;
typedef __attribute__((ext_vector_type(4))) float f32x4;
typedef __attribute__((ext_vector_type(8))) short bf16x8;

#define DI static __device__ __forceinline__

DI u16 f2bf(float f) {
    unsigned u = __builtin_bit_cast(unsigned, f);
    return (u16)((u + 0x7fffu + ((u >> 16) & 1u)) >> 16);  // RNE
}

DI bf16x8 cvt8(float4 a, float4 b) {
    unsigned r0, r1, r2, r3;
    asm("v_cvt_pk_bf16_f32 %0, %1, %2" : "=v"(r0) : "v"(a.x), "v"(a.y));
    asm("v_cvt_pk_bf16_f32 %0, %1, %2" : "=v"(r1) : "v"(a.z), "v"(a.w));
    asm("v_cvt_pk_bf16_f32 %0, %1, %2" : "=v"(r2) : "v"(b.x), "v"(b.y));
    asm("v_cvt_pk_bf16_f32 %0, %1, %2" : "=v"(r3) : "v"(b.z), "v"(b.w));
    unsigned tmp[4] = {r0, r1, r2, r3};
    return *(const bf16x8*)tmp;
}

// B-operand image: element (k,n) at (((k>>5)*128+n)*4 + (((k>>3)&3)^((n>>1)&3)))*8 + (k&7)
DI int imgIdx(int k, int n) {
    return (((k >> 5) * 128 + n) * 4 + (((k >> 3) & 3) ^ ((n >> 1) & 3))) * 8 + (k & 7);
}
// B fragment (16B) direct from a weight/edge image in global memory.
DI bf16x8 wfragG(const u16* __restrict__ img, int kc, int tt, int l15, int quad) {
    return *(const bf16x8*)&img[(((kc * 128 + tt * 16 + l15) * 4) + (quad ^ ((l15 >> 1) & 3))) * 8];
}

#define MFMA16(a, b, c) __builtin_amdgcn_mfma_f32_16x16x32_bf16(a, b, c, 0, 0, 0)

// ---------------------------------------------------------------- prep 1
__global__ __launch_bounds__(256) void k_prep1(
    const float* __restrict__ linkW, const float* __restrict__ resetW,
    const float* __restrict__ updateW, const float* __restrict__ transW,
    const float* __restrict__ attW1, const float* __restrict__ outW,
    float* __restrict__ W2, u16* __restrict__ linkImg, u16* __restrict__ WrImg,
    u16* __restrict__ WzImg, u16* __restrict__ WhImg, u16* __restrict__ attW1Img,
    u16* __restrict__ outWImg)
{
    int blk = blockIdx.x, t = threadIdx.x;
    if (blk < 256) {
        int idx = blk * 256 + t;
        int out = idx >> 2, q = idx & 3;
        int r = out >> 7, c = out & 127;
        const float* ar = linkW + r * 128 + q * 32;
        float acc = 0.f;
#pragma unroll
        for (int k = 0; k < 32; k++) acc += ar[k] * linkW[(q * 32 + k) * 128 + c];
        acc += __shfl_xor(acc, 1);
        acc += __shfl_xor(acc, 2);
        if (q == 0) W2[out] = acc;
    } else {
        const float* src; u16* dst; int base;
        if (blk < 260)      { src = resetW;  dst = WrImg;    base = 256; }
        else if (blk < 264) { src = updateW; dst = WzImg;    base = 260; }
        else if (blk < 268) { src = transW;  dst = WhImg;    base = 264; }
        else if (blk < 270) { src = linkW;   dst = linkImg;  base = 268; }
        else if (blk < 272) { src = attW1;   dst = attW1Img; base = 270; }
        else                { src = outW;    dst = outWImg;  base = 272; }
        int off = (blk - base) * 8192;
        for (int i = 0; i < 32; i++) {
            int e = off + t + i * 256;
            int k = e >> 7, n = e & 127;
            dst[imgIdx(k, n)] = f2bf(src[e]);
        }
    }
}

// ---------------------------------------------------------------- prep 2
__global__ __launch_bounds__(256) void k_prep2(
    const float* __restrict__ linkW, const float* __restrict__ linkb,
    const float* __restrict__ W2, u16* __restrict__ W3Img, float* __restrict__ ebias)
{
    int blk = blockIdx.x, t = threadIdx.x;
    if (blk < 256) {
        int idx = blk * 256 + t;
        int out = idx >> 2, q = idx & 3;
        int r = out >> 7, c = out & 127;
        const float* ar = W2 + r * 128 + q * 32;
        float acc = 0.f;
#pragma unroll
        for (int k = 0; k < 32; k++) acc += ar[k] * linkW[(q * 32 + k) * 128 + c];
        acc += __shfl_xor(acc, 1);
        acc += __shfl_xor(acc, 2);
        if (q == 0) W3Img[imgIdx(r, c)] = f2bf(acc);
    } else if (t < 128) {
        float acc = linkb[t];
#pragma unroll 8
        for (int k = 0; k < 128; k++) acc += linkb[k] * (W2[k * 128 + t] + linkW[k * 128 + t]);
        ebias[t] = acc;
    }
}

// ---------------------------------------------------------------- E transpose (+edge resid)
__global__ __launch_bounds__(256) void k_te(
    const float* __restrict__ E0, u16* __restrict__ Eswz, float* __restrict__ resid)
{
    __shared__ alignas(16) u16 sT[4096];
    __shared__ float sCol[128];
    int t = threadIdx.x, kc = blockIdx.x, b = blockIdx.y;
    const float* Eb = E0 + (size_t)b * 262144 + (size_t)kc * 32 * 128;
    if (t < 128) sCol[t] = 0.f;
    float part[4] = {0.f, 0.f, 0.f, 0.f};
    int ncol = (t & 31) * 4;
    for (int i = 0; i < 4; i++) {
        int f4i = t + i * 256;
        int k5 = f4i >> 5;
        float4 v = *(const float4*)&Eb[k5 * 128 + ncol];
        int g = k5 >> 3, o = k5 & 7;
        float vv[4] = {v.x, v.y, v.z, v.w};
#pragma unroll
        for (int j = 0; j < 4; j++) {
            int n = ncol + j;
            sT[(n * 4 + (g ^ ((n >> 1) & 3))) * 8 + o] = f2bf(vv[j]);
            part[j] += vv[j];
        }
    }
    __syncthreads();
#pragma unroll
    for (int j = 0; j < 4; j++) atomicAdd(&sCol[ncol + j], part[j]);
    u16* dst = Eswz + (size_t)b * 262144 + (size_t)kc * 4096;
    ((uint4*)dst)[t] = ((const uint4*)sT)[t];
    ((uint4*)dst)[t + 256] = ((const uint4*)sT)[t + 256];
    __syncthreads();
    if (t < 128) atomicAdd(&resid[b * 128 + t], sCol[t]);
}

// ---------------------------------------------------------------- FUSED: G0 = A@E0 (32 rows),
// then 3 GRU steps + attention for both 16-row groups. Wave (tg,kh) in G0;
// wave = tt-pair in steps, iterating rg 0/1 so each weight fragment feeds
// 2x MFMAs. sBuf rows: 0-31 a | 32-63 p | 64-95 r*p.
__global__ __launch_bounds__(256, 2) void k_main(
    const float* __restrict__ A, const u16* __restrict__ Eswz,
    const float* __restrict__ p0,
    const u16* __restrict__ linkImg, const u16* __restrict__ WrImg,
    const u16* __restrict__ WzImg, const u16* __restrict__ WhImg,
    const u16* __restrict__ attW1Img, const u16* __restrict__ outWImg,
    const float* __restrict__ link_b, const float* __restrict__ reset_b,
    const float* __restrict__ update_b, const float* __restrict__ trans_b,
    const float* __restrict__ att_b1, const float* __restrict__ att_W2,
    const float* __restrict__ att_b2, const float* __restrict__ out_b,
    float* __restrict__ atten, float* __restrict__ outPool,
    float* __restrict__ resid)
{
    __shared__ float sAcc2[2][2][16 * 65];             // 16.6 KB: [tg][rg] K-half-1 partials
    __shared__ float sRs[2][32];                       // [kh][row] rowsum partials
    __shared__ alignas(16) u16 sBuf[96 * 136];         // 26.1 KB operand buffer
    __shared__ float sRed[32];

    int t = threadIdx.x, wid = t >> 6, lane = t & 63, l15 = lane & 15, quad = lane >> 4;
    int tg = wid >> 1, kh = wid & 1;                   // G0: tt-group / K-half
    int bx = blockIdx.x;
    int g = bx >> 7, rmod = bx & 127;
    int b = (rmod & 7) + 8 * g;                        // XCD-affine batch mapping
    int s = (rmod >> 3) & 15;
    size_t r0 = (size_t)b * 512 + (size_t)s * 32;

    // ================= phase G0: acc = A[32 rows] @ E0; B frags reused for both row-groups
    {
        const u16* Eb = Eswz + (size_t)b * 262144;
        const float* Ar0 = A + (r0 + l15) * 2048 + kh * 1024;
        const float* Ar1 = A + (r0 + 16 + l15) * 2048 + kh * 1024;

        f32x4 acc[2][4];
#pragma unroll
        for (int rg = 0; rg < 2; rg++)
#pragma unroll
            for (int i = 0; i < 4; i++) acc[rg][i] = (f32x4){0.f, 0.f, 0.f, 0.f};
        float rs0 = 0.f, rs1 = 0.f;

        float4 x0 = *(const float4*)&Ar0[quad * 8];
        float4 y0 = *(const float4*)&Ar0[quad * 8 + 4];
        float4 x1 = *(const float4*)&Ar1[quad * 8];
        float4 y1 = *(const float4*)&Ar1[quad * 8 + 4];
        rs0 += x0.x + x0.y + x0.z + x0.w + y0.x + y0.y + y0.z + y0.w;
        rs1 += x1.x + x1.y + x1.z + x1.w + y1.x + y1.y + y1.z + y1.w;
        bf16x8 aF0 = cvt8(x0, y0), aF1 = cvt8(x1, y1);
        bf16x8 bc[4];
#pragma unroll
        for (int tt = 0; tt < 4; tt++) bc[tt] = wfragG(Eb, kh * 32, tg * 4 + tt, l15, quad);

        for (int kc = 0; kc < 32; kc++) {
            float4 xn0, yn0, xn1, yn1; bf16x8 bn[4];
            if (kc < 31) {
                xn0 = *(const float4*)&Ar0[(kc + 1) * 32 + quad * 8];
                yn0 = *(const float4*)&Ar0[(kc + 1) * 32 + quad * 8 + 4];
                xn1 = *(const float4*)&Ar1[(kc + 1) * 32 + quad * 8];
                yn1 = *(const float4*)&Ar1[(kc + 1) * 32 + quad * 8 + 4];
#pragma unroll
                for (int tt = 0; tt < 4; tt++)
                    bn[tt] = wfragG(Eb, kh * 32 + kc + 1, tg * 4 + tt, l15, quad);
            }
#pragma unroll
            for (int tt = 0; tt < 4; tt++) {
                acc[0][tt] = MFMA16(aF0, bc[tt], acc[0][tt]);
                acc[1][tt] = MFMA16(aF1, bc[tt], acc[1][tt]);
            }
            if (kc < 31) {
                rs0 += xn0.x + xn0.y + xn0.z + xn0.w + yn0.x + yn0.y + yn0.z + yn0.w;
                rs1 += xn1.x + xn1.y + xn1.z + xn1.w + yn1.x + yn1.y + yn1.z + yn1.w;
                aF0 = cvt8(xn0, yn0); aF1 = cvt8(xn1, yn1);
#pragma unroll
                for (int tt = 0; tt < 4; tt++) bc[tt] = bn[tt];
            }
        }
        rs0 += __shfl_xor(rs0, 16); rs0 += __shfl_xor(rs0, 32);
        rs1 += __shfl_xor(rs1, 16); rs1 += __shfl_xor(rs1, 32);
        if (quad == 0 && tg == 0) { sRs[kh][l15] = rs0; sRs[kh][16 + l15] = rs1; }
        if (kh == 1) {
#pragma unroll
            for (int rg = 0; rg < 2; rg++)
#pragma unroll
                for (int tt = 0; tt < 4; tt++)
#pragma unroll
                    for (int r = 0; r < 4; r++)
                        sAcc2[tg][rg][(quad * 4 + r) * 65 + tt * 16 + l15] = acc[rg][tt][r];
        }
        if (t < 32) sRed[t] = 0.f;                     // attention accumulator
        __syncthreads();
        if (kh == 0) {
            // combine K-halves, emit bf16 G0 into sBuf rows 0-31
#pragma unroll
            for (int rg = 0; rg < 2; rg++)
#pragma unroll
                for (int tt = 0; tt < 4; tt++)
#pragma unroll
                    for (int r = 0; r < 4; r++) {
                        float v = acc[rg][tt][r] + sAcc2[tg][rg][(quad * 4 + r) * 65 + tt * 16 + l15];
                        sBuf[(rg * 16 + quad * 4 + r) * 136 + tg * 64 + tt * 16 + l15] = f2bf(v);
                    }
        } else {
            // K-half-1 waves (128 threads) stage p0 -> sBuf rows 32-63
            int idx = tg * 64 + lane;                  // 0..127
            int row = idx >> 2, cq = (idx & 3) * 32;
            const float* pr = &p0[(r0 + row) * 128 + cq];
#pragma unroll
            for (int j = 0; j < 4; j++) {
                float4 x = *(const float4*)&pr[j * 8];
                float4 y = *(const float4*)&pr[j * 8 + 4];
                *(bf16x8*)&sBuf[(32 + row) * 136 + cq + j * 8] = cvt8(x, y);
            }
        }
    }
    __syncthreads();

    // ================= steps: 3 GRU steps + attention; wave owns tt-pair, loops rg 0/1
    int ttA = wid * 2, ttB = wid * 2 + 1;
    int colA = ttA * 16 + l15, colB = ttB * 16 + l15;

    // own-col fp32 p state for both row-groups
    f32x4 pS[2][2];
#pragma unroll
    for (int rg = 0; rg < 2; rg++)
#pragma unroll
        for (int j = 0; j < 2; j++)
#pragma unroll
            for (int r = 0; r < 4; r++)
                pS[rg][j][r] = p0[(r0 + rg * 16 + quad * 4 + r) * 128 + (wid * 2 + j) * 16 + l15];
    // node residual: sum over this block's 32 rows, own cols
    {
        float s0 = pS[0][0][0] + pS[0][0][1] + pS[0][0][2] + pS[0][0][3]
                 + pS[1][0][0] + pS[1][0][1] + pS[1][0][2] + pS[1][0][3];
        float s1 = pS[0][1][0] + pS[0][1][1] + pS[0][1][2] + pS[0][1][3]
                 + pS[1][1][0] + pS[1][1][1] + pS[1][1][2] + pS[1][1][3];
        s0 += __shfl_xor(s0, 16); s0 += __shfl_xor(s0, 32);
        s1 += __shfl_xor(s1, 16); s1 += __shfl_xor(s1, 32);
        if (quad == 0) {
            atomicAdd(&resid[b * 128 + colA], s0);
            atomicAdd(&resid[b * 128 + colB], s1);
        }
    }
    float sv[2][4];
#pragma unroll
    for (int rg = 0; rg < 2; rg++)
#pragma unroll
        for (int r = 0; r < 4; r++)
            sv[rg][r] = sRs[0][rg * 16 + quad * 4 + r] + sRs[1][rg * 16 + quad * 4 + r];
    float lbA = link_b[colA], lbB = link_b[colB];
    float rbA = reset_b[colA], rbB = reset_b[colB];
    float ubA = update_b[colA], ubB = update_b[colB];
    float tbA = trans_b[colA], tbB = trans_b[colB];

    f32x4 zero4 = {0.f, 0.f, 0.f, 0.f};
    int fcol = quad * 8;
    for (int step = 0; step < 3; step++) {
        // ---- phase 1: a_new = a @ linkW + rowsum*link_b (weights shared across rgs)
        f32x4 cc[2][2];
#pragma unroll
        for (int rg = 0; rg < 2; rg++) { cc[rg][0] = zero4; cc[rg][1] = zero4; }
#pragma unroll
        for (int kc = 0; kc < 4; kc++) {
            bf16x8 wla = wfragG(linkImg, kc, ttA, l15, quad);
            bf16x8 wlb = wfragG(linkImg, kc, ttB, l15, quad);
            bf16x8 af0 = *(const bf16x8*)&sBuf[l15 * 136 + kc * 32 + fcol];
            bf16x8 af1 = *(const bf16x8*)&sBuf[(16 + l15) * 136 + kc * 32 + fcol];
            cc[0][0] = MFMA16(af0, wla, cc[0][0]); cc[0][1] = MFMA16(af0, wlb, cc[0][1]);
            cc[1][0] = MFMA16(af1, wla, cc[1][0]); cc[1][1] = MFMA16(af1, wlb, cc[1][1]);
        }
        __syncthreads();             // reads of rows 0-31 done before rewrite
#pragma unroll
        for (int rg = 0; rg < 2; rg++)
#pragma unroll
            for (int r = 0; r < 4; r++) {
                sBuf[(rg * 16 + quad * 4 + r) * 136 + colA] = f2bf(cc[rg][0][r] + sv[rg][r] * lbA);
                sBuf[(rg * 16 + quad * 4 + r) * 136 + colB] = f2bf(cc[rg][1][r] + sv[rg][r] * lbB);
            }
        __syncthreads();             // a_new visible
        // ---- phase 2: r, z; K=256 over [a_new(0-31), p(32-63)]
        f32x4 rr[2][2], zz[2][2];
#pragma unroll
        for (int rg = 0; rg < 2; rg++) { rr[rg][0] = zero4; rr[rg][1] = zero4; zz[rg][0] = zero4; zz[rg][1] = zero4; }
#pragma unroll 4
        for (int kc = 0; kc < 8; kc++) {
            int base = (kc >> 2) * 32;
            bf16x8 wra = wfragG(WrImg, kc, ttA, l15, quad);
            bf16x8 wrb = wfragG(WrImg, kc, ttB, l15, quad);
            bf16x8 wza = wfragG(WzImg, kc, ttA, l15, quad);
            bf16x8 wzb = wfragG(WzImg, kc, ttB, l15, quad);
            bf16x8 af0 = *(const bf16x8*)&sBuf[(base + l15) * 136 + (kc & 3) * 32 + fcol];
            bf16x8 af1 = *(const bf16x8*)&sBuf[(base + 16 + l15) * 136 + (kc & 3) * 32 + fcol];
            rr[0][0] = MFMA16(af0, wra, rr[0][0]); rr[0][1] = MFMA16(af0, wrb, rr[0][1]);
            zz[0][0] = MFMA16(af0, wza, zz[0][0]); zz[0][1] = MFMA16(af0, wzb, zz[0][1]);
            rr[1][0] = MFMA16(af1, wra, rr[1][0]); rr[1][1] = MFMA16(af1, wrb, rr[1][1]);
            zz[1][0] = MFMA16(af1, wza, zz[1][0]); zz[1][1] = MFMA16(af1, wzb, zz[1][1]);
        }
#pragma unroll
        for (int rg = 0; rg < 2; rg++)
#pragma unroll
            for (int r = 0; r < 4; r++) {
                float rvA = 1.f / (1.f + __expf(-(rr[rg][0][r] + rbA)));
                float rvB = 1.f / (1.f + __expf(-(rr[rg][1][r] + rbB)));
                zz[rg][0][r] = 1.f / (1.f + __expf(-(zz[rg][0][r] + ubA)));
                zz[rg][1][r] = 1.f / (1.f + __expf(-(zz[rg][1][r] + ubB)));
                sBuf[(64 + rg * 16 + quad * 4 + r) * 136 + colA] = f2bf(rvA * pS[rg][0][r]);
                sBuf[(64 + rg * 16 + quad * 4 + r) * 136 + colB] = f2bf(rvB * pS[rg][1][r]);
            }
        __syncthreads();             // r*p (rows 64-95) visible
        // ---- phase 3: h; K=256 over [a_new(0-31), r*p(64-95)]
        f32x4 hh[2][2];
#pragma unroll
        for (int rg = 0; rg < 2; rg++) { hh[rg][0] = zero4; hh[rg][1] = zero4; }
#pragma unroll 4
        for (int kc = 0; kc < 8; kc++) {
            int base = (kc >> 2) * 64;
            bf16x8 wha = wfragG(WhImg, kc, ttA, l15, quad);
            bf16x8 whb = wfragG(WhImg, kc, ttB, l15, quad);
            bf16x8 af0 = *(const bf16x8*)&sBuf[(base + l15) * 136 + (kc & 3) * 32 + fcol];
            bf16x8 af1 = *(const bf16x8*)&sBuf[(base + 16 + l15) * 136 + (kc & 3) * 32 + fcol];
            hh[0][0] = MFMA16(af0, wha, hh[0][0]); hh[0][1] = MFMA16(af0, whb, hh[0][1]);
            hh[1][0] = MFMA16(af1, wha, hh[1][0]); hh[1][1] = MFMA16(af1, whb, hh[1][1]);
        }
#pragma unroll
        for (int rg = 0; rg < 2; rg++)
#pragma unroll
            for (int r = 0; r < 4; r++) {
                float h1 = tanhf(hh[rg][0][r] + tbA), h2 = tanhf(hh[rg][1][r] + tbB);
                pS[rg][0][r] = (1.f - zz[rg][0][r]) * pS[rg][0][r] + zz[rg][0][r] * h1;
                pS[rg][1][r] = (1.f - zz[rg][1][r]) * pS[rg][1][r] + zz[rg][1][r] * h2;
                sBuf[(32 + rg * 16 + quad * 4 + r) * 136 + colA] = f2bf(pS[rg][0][r]);
                sBuf[(32 + rg * 16 + quad * 4 + r) * 136 + colB] = f2bf(pS[rg][1][r]);
            }
        __syncthreads();             // p (rows 32-63) visible
    }
    // ---- attention + out; A-operand = p3 (rows 32-63), weights shared across rgs
    f32x4 at[2][2], oo[2][2];
#pragma unroll
    for (int rg = 0; rg < 2; rg++) { at[rg][0] = zero4; at[rg][1] = zero4; oo[rg][0] = zero4; oo[rg][1] = zero4; }
#pragma unroll
    for (int kc = 0; kc < 4; kc++) {
        bf16x8 wa  = wfragG(attW1Img, kc, ttA, l15, quad);
        bf16x8 wb  = wfragG(attW1Img, kc, ttB, l15, quad);
        bf16x8 woa = wfragG(outWImg,  kc, ttA, l15, quad);
        bf16x8 wob = wfragG(outWImg,  kc, ttB, l15, quad);
        bf16x8 pf0 = *(const bf16x8*)&sBuf[(32 + l15) * 136 + kc * 32 + fcol];
        bf16x8 pf1 = *(const bf16x8*)&sBuf[(48 + l15) * 136 + kc * 32 + fcol];
        at[0][0] = MFMA16(pf0, wa, at[0][0]);  at[0][1] = MFMA16(pf0, wb, at[0][1]);
        oo[0][0] = MFMA16(pf0, woa, oo[0][0]); oo[0][1] = MFMA16(pf0, wob, oo[0][1]);
        at[1][0] = MFMA16(pf1, wa, at[1][0]);  at[1][1] = MFMA16(pf1, wb, at[1][1]);
        oo[1][0] = MFMA16(pf1, woa, oo[1][0]); oo[1][1] = MFMA16(pf1, wob, oo[1][1]);
    }
    float b1A = att_b1[colA], b1B = att_b1[colB];
    float w2A = att_W2[colA], w2B = att_W2[colB];
    float obA = out_b[colA],  obB = out_b[colB];
#pragma unroll
    for (int rg = 0; rg < 2; rg++)
#pragma unroll
        for (int r = 0; r < 4; r++) {
            float pr = tanhf(at[rg][0][r] + b1A) * w2A + tanhf(at[rg][1][r] + b1B) * w2B;
            outPool[(r0 + rg * 16 + quad * 4 + r) * 128 + colA] = tanhf(oo[rg][0][r] + obA);
            outPool[(r0 + rg * 16 + quad * 4 + r) * 128 + colB] = tanhf(oo[rg][1][r] + obB);
            float v = pr;
            v += __shfl_xor(v, 1); v += __shfl_xor(v, 2);
            v += __shfl_xor(v, 4); v += __shfl_xor(v, 8);
            if (l15 == 0) atomicAdd(&sRed[rg * 16 + quad * 4 + r], v);
        }
    __syncthreads();
    if (t < 32) atten[r0 + t] = sRed[t] + att_b2[0];
}

// ---------------------------------------------------------------- edges out: E0@W3 + ebias
// M=32: each W3 fragment feeds both row-groups (halves weight traffic).
__global__ __launch_bounds__(64) void k_eout(
    const float* __restrict__ E0, const u16* __restrict__ W3Img,
    const float* __restrict__ ebias, float* __restrict__ Eout)
{
    int t = threadIdx.x, l15 = t & 15, quad = t >> 4;
    size_t r0 = (size_t)blockIdx.x * 32;
    bf16x8 eF[2][4];
#pragma unroll
    for (int rg = 0; rg < 2; rg++)
#pragma unroll
        for (int kc = 0; kc < 4; kc++) {
            const float* er = &E0[(r0 + rg * 16 + l15) * 128 + kc * 32 + quad * 8];
            eF[rg][kc] = cvt8(*(const float4*)er, *(const float4*)(er + 4));
        }
    f32x4 acc[2][8];
#pragma unroll
    for (int rg = 0; rg < 2; rg++)
#pragma unroll
        for (int i = 0; i < 8; i++) acc[rg][i] = (f32x4){0.f, 0.f, 0.f, 0.f};
    {
        bf16x8 wc[8], wn[8];
#pragma unroll
        for (int tt = 0; tt < 8; tt++) wc[tt] = wfragG(W3Img, 0, tt, l15, quad);
#pragma unroll
        for (int kc = 0; kc < 4; kc++) {
            if (kc < 3)
#pragma unroll
                for (int tt = 0; tt < 8; tt++) wn[tt] = wfragG(W3Img, kc + 1, tt, l15, quad);
#pragma unroll
            for (int tt = 0; tt < 8; tt++) {
                acc[0][tt] = MFMA16(eF[0][kc], wc[tt], acc[0][tt]);
                acc[1][tt] = MFMA16(eF[1][kc], wc[tt], acc[1][tt]);
            }
            if (kc < 3)
#pragma unroll
                for (int tt = 0; tt < 8; tt++) wc[tt] = wn[tt];
        }
    }
#pragma unroll
    for (int tt = 0; tt < 8; tt++) {
        int col = tt * 16 + l15; float eb = ebias[col];
#pragma unroll
        for (int rg = 0; rg < 2; rg++)
#pragma unroll
            for (int r = 0; r < 4; r++)
                Eout[(r0 + rg * 16 + quad * 4 + r) * 128 + col] = acc[rg][tt][r] + eb;
    }
}

// ---------------------------------------------------------------- softmax-pool + residual
__global__ __launch_bounds__(1024) void k_fin(
    const float* __restrict__ atten, const float* __restrict__ outPool,
    const float* __restrict__ resid,
    float* __restrict__ outRes, float* __restrict__ outMul)
{
    __shared__ float swv[512];
    __shared__ float sred[512];
    __shared__ float sacc[8][128];
    int t = threadIdx.x, b = blockIdx.x;
    float a = 0.f;
    if (t < 512) { a = atten[b * 512 + t]; sred[t] = a; }
    __syncthreads();
    for (int s = 256; s > 0; s >>= 1) { if (t < s) sred[t] = fmaxf(sred[t], sred[t + s]); __syncthreads(); }
    float mx = sred[0]; __syncthreads();
    if (t < 512) { float e = __expf(a - mx); swv[t] = e; sred[t] = e; }
    __syncthreads();
    for (int s = 256; s > 0; s >>= 1) { if (t < s) sred[t] += sred[t + s]; __syncthreads(); }
    float Z = sred[0]; __syncthreads();
    int col = t & 127, q = t >> 7;                     // 8 row-groups of 64
    const float* op = outPool + ((size_t)b * 512 + q * 64) * 128 + col;
    float accM = 0.f;
#pragma unroll 8
    for (int n = 0; n < 64; n++) accM += swv[q * 64 + n] * op[(size_t)n * 128];
    sacc[q][col] = accM;
    __syncthreads();
    if (t < 128) {
        float mulv = (sacc[0][t] + sacc[1][t] + sacc[2][t] + sacc[3][t] +
                      sacc[4][t] + sacc[5][t] + sacc[6][t] + sacc[7][t]) / Z;
        float rv = resid[b * 128 + t] * (1.f / 2560.f);
        outMul[b * 128 + t] = mulv;
        outRes[b * 128 + t] = fmaxf(0.f, tanhf(mulv) + rv);
    }
}

// ================================================================ launch
extern "C" void kernel_launch(void* const* d_in, const int* in_sizes, int n_in,
                              void* d_out, int out_size, void* d_ws, size_t ws_size,
                              hipStream_t stream)
{
    const float* prop0  = (const float*)d_in[0];
    const float* edge0  = (const float*)d_in[1];
    const float* Amat   = (const float*)d_in[2];
    const float* linkW  = (const float*)d_in[4];
    const float* linkb  = (const float*)d_in[5];
    const float* resetW = (const float*)d_in[6];
    const float* resetb = (const float*)d_in[7];
    const float* updateW= (const float*)d_in[8];
    const float* updateb= (const float*)d_in[9];
    const float* transW = (const float*)d_in[10];
    const float* transb = (const float*)d_in[11];
    const float* attW1  = (const float*)d_in[12];
    const float* attb1  = (const float*)d_in[13];
    const float* attW2  = (const float*)d_in[14];
    const float* attb2  = (const float*)d_in[15];
    const float* outW   = (const float*)d_in[16];
    const float* outb   = (const float*)d_in[17];

    char* w = (char*)d_ws;
    float* ws_atten   = (float*)(w + 4259840);        //    65,536 B
    float* ws_resid   = (float*)(w + 4325376);        //    16,384 B
    float* ws_W2      = (float*)(w + 4341760);        //    65,536 B
    float* ws_ebias   = (float*)(w + 4407296);        //       512 B
    u16*   ws_linkImg = (u16*)(w + 4407808);          //    32,768 B
    u16*   ws_W3Img   = (u16*)(w + 4440576);          //    32,768 B
    u16*   ws_WrImg   = (u16*)(w + 4473344);          //    65,536 B
    u16*   ws_WzImg   = (u16*)(w + 4538880);          //    65,536 B
    u16*   ws_WhImg   = (u16*)(w + 4604416);          //    65,536 B
    u16*   ws_attW1Img= (u16*)(w + 4669952);          //    32,768 B
    u16*   ws_outWImg = (u16*)(w + 4702720);          //    32,768 B (~4.7 MB)

    float* out_res  = (float*)d_out;
    float* out_mul  = out_res + 4096;
    float* out_edge = out_res + 8192;
    // Scratch inside d_out edge region (dead until k_eout, which runs last):
    u16*   Eswz     = (u16*)out_edge;                 // 16.78 MB
    float* outPool  = out_edge + 4194304;             // next 8.39 MB

    hipMemsetAsync(ws_resid, 0, 32 * 128 * sizeof(float), stream);
    k_prep1<<<274, 256, 0, stream>>>(linkW, resetW, updateW, transW, attW1, outW,
                                     ws_W2, ws_linkImg, ws_WrImg, ws_WzImg, ws_WhImg,
                                     ws_attW1Img, ws_outWImg);
    k_prep2<<<257, 256, 0, stream>>>(linkW, linkb, ws_W2, ws_W3Img, ws_ebias);
    k_te<<<dim3(64, 32), 256, 0, stream>>>(edge0, Eswz, ws_resid);
    k_main<<<512, 256, 0, stream>>>(Amat, Eswz, prop0,
                                    ws_linkImg, ws_WrImg, ws_WzImg, ws_WhImg,
                                    ws_attW1Img, ws_outWImg,
                                    linkb, resetb, updateb, transb,
                                    attb1, attW2, attb2, outb,
                                    ws_atten, outPool, ws_resid);
    k_fin<<<32, 1024, 0, stream>>>(ws_atten, outPool, ws_resid, out_res, out_mul);
    k_eout<<<2048, 64, 0, stream>>>(edge0, ws_W3Img, ws_ebias, out_edge);
}